// Round 5
// baseline (387.893 us; speedup 1.0000x reference)
//
#include <hip/hip_runtime.h>

// spectralAgg: per-(batch,patch) DANet channel attention, 8x8 grid of 64x64
// patches of (8,64,512,512) fp32.
// E = p p^T (split-bf16: G + S + S^T, S = hi*lo^T), A = softmax(-E) (gamma
// folded), out = A p (bf16 MFMA).
// R5: 512-thread WGs (16 waves/CU), K-split Gram across wave pairs, fully
// coalesced loaders (16-lane x 256B segments), padded phase-3 tile, single-
// buffer reg prefetch with lgkm-only barriers.

#define NW   512
#define HWs  262144
#define NS   16           // stages per phase: tile = 4 patch rows = 256 i

typedef __attribute__((ext_vector_type(8)))  __bf16 bf8;
typedef __attribute__((ext_vector_type(4)))  __bf16 bf4;
typedef __attribute__((ext_vector_type(16))) float  f32x16;

#define F4E(v,j) ((j)==0?(v).x:(j)==1?(v).y:(j)==2?(v).z:(v).w)

// barrier waiting only LDS ops: global prefetch stays in flight across it
__device__ __forceinline__ void bar_lgkm() {
  asm volatile("s_waitcnt lgkmcnt(0)" ::: "memory");
  __builtin_amdgcn_s_barrier();
}

extern "C" __global__ __launch_bounds__(512, 4)
void spectralAgg_kernel(const float* __restrict__ x, const float* __restrict__ g,
                        float* __restrict__ out) {
  __shared__ char lds[65536];
  char* sH = lds;            // P1: hi stage 32KB [64c][512B]; later E_lds 16KB, sT 36.9KB
  char* sL = lds + 32768;    // P1: lo stage 32KB; later S_lds 16KB
  char* sA = lds + 49152;    // P3: attention bf16 [64c][256B], swizzled (16KB)

  const int T   = threadIdx.x;
  const int wv8 = T >> 6;          // 0..7
  const int l   = T & 63;
  const int l31 = l & 31;
  const int hh  = l >> 5;
  const int g2  = (T >> 4) & 3;
  const int e16 = T & 15;

  const int wg = blockIdx.x;       // 512 = 8 batches * 64 patches
  const int b  = wg >> 6;
  const int pp = wg & 63;
  const size_t pbase = (size_t)b*64*HWs + (size_t)((pp>>3)*64)*NW + (size_t)((pp&7)*64);
  const float* xp = x + pbase;
  float* op = out + pbase;

  // ================= Phase 1: Gram via split-bf16 MFMA (K-split waves) ======
  // loader inst k: channel c = k*8+wv8, patch-row st*4+g2, 16 lanes x 16B contiguous
  float4 ra[8];
#pragma unroll
  for (int k = 0; k < 8; ++k)
    ra[k] = *(const float4*)(xp + (size_t)(k*8+wv8)*HWs + (size_t)g2*NW + e16*4);

  const int q  = wv8 & 3;          // quadrant of E
  const int kh = wv8 >> 2;         // K-half
  const int ct = q >> 1, dt = q & 1;
  const char* pA  = sH + (size_t)(ct*32+l31)*512 + kh*256;
  const char* pBh = sH + (size_t)(dt*32+l31)*512 + kh*256;
  const char* pBl = sL + (size_t)(dt*32+l31)*512 + kh*256;
  const int swz1 = (l31 & 15) << 4;

  f32x16 accG, accS;
#pragma unroll
  for (int r = 0; r < 16; ++r) { accG[r] = 0.f; accS[r] = 0.f; }

  for (int st = 0; st < NS; ++st) {
    // convert current tile -> hi/lo LDS
#pragma unroll
    for (int k = 0; k < 8; ++k) {
      const int c = k*8 + wv8;
      const float4 v = ra[k];
      bf4 h, lo;
      h[0]=(__bf16)v.x; h[1]=(__bf16)v.y; h[2]=(__bf16)v.z; h[3]=(__bf16)v.w;
      lo[0]=(__bf16)(v.x-(float)h[0]); lo[1]=(__bf16)(v.y-(float)h[1]);
      lo[2]=(__bf16)(v.z-(float)h[2]); lo[3]=(__bf16)(v.w-(float)h[3]);
      const int off = c*512 + ((g2*128 + e16*8) ^ ((c&15)<<4));
      *(bf4*)(sH+off) = h;
      *(bf4*)(sL+off) = lo;
    }
    // prefetch next tile (in flight across both barriers + MFMA)
    const int sn = (st+1 < NS) ? st+1 : st;
#pragma unroll
    for (int k = 0; k < 8; ++k)
      ra[k] = *(const float4*)(xp + (size_t)(k*8+wv8)*HWs + (size_t)(sn*4+g2)*NW + e16*4);
    bar_lgkm();
#pragma unroll
    for (int k0 = 0; k0 < 8; ++k0) {
      const int off = (k0*32 + hh*16) ^ swz1;
      const bf8 a  = *(const bf8*)(pA  + off);
      const bf8 bh = *(const bf8*)(pBh + off);
      const bf8 bl = *(const bf8*)(pBl + off);
      accG = __builtin_amdgcn_mfma_f32_32x32x16_bf16(a, bh, accG, 0, 0, 0);
      accS = __builtin_amdgcn_mfma_f32_32x32x16_bf16(a, bl, accS, 0, 0, 0);
    }
    bar_lgkm();
  }

  // ---- E = G + S + S^T, reduced over K-halves (LDS overlays) ----
  float* E_lds = (float*)sH;       // 16KB [64][64]
  float* S_lds = (float*)sL;       // 16KB [64][64]
  if (kh == 0) {
#pragma unroll
    for (int r = 0; r < 16; ++r) {
      const int cr = ct*32 + (r&3) + ((r>>2)<<3) + (hh<<2);
      const int d  = dt*32 + l31;
      S_lds[cr*64+d] = accS[r];
      E_lds[cr*64+d] = accG[r] + accS[r];
    }
  }
  bar_lgkm();
  if (kh == 1) {
#pragma unroll
    for (int r = 0; r < 16; ++r) {
      const int cr = ct*32 + (r&3) + ((r>>2)<<3) + (hh<<2);
      const int d  = dt*32 + l31;
      S_lds[cr*64+d] += accS[r];
      E_lds[cr*64+d] += accG[r] + accS[r];
    }
  }
  bar_lgkm();
#pragma unroll
  for (int r = 0; r < 8; ++r) {    // E += S^T
    const int c = T >> 3, d = (T&7)*8 + r;
    E_lds[c*64+d] += S_lds[d*64+c];
  }
  bar_lgkm();

  // ============ Phase 2: softmax(-E) -> sA; phase-3 stage-0 prefetched ======
  // phase-3 loader: group (quad,rwb): quad = (wv8*4+g2)&15, rows {rwb, rwb+2}
  const int quad = (wv8*4+g2) & 15;
  const int rwb  = (wv8*4+g2) >> 4;
#pragma unroll
  for (int k = 0; k < 8; ++k) {
    const int cc = k & 3, mm = k >> 2;
    ra[k] = *(const float4*)(xp + (size_t)(quad*4+cc)*HWs + (size_t)(rwb+mm*2)*NW + e16*4);
  }

  const float gs = 1.0f + g[0];
#pragma unroll 1
  for (int rr = 0; rr < 8; ++rr) {
    const int c = wv8*8 + rr;
    const float e = E_lds[c*64 + l];
    float mn = e;
#pragma unroll
    for (int o = 32; o; o >>= 1) mn = fminf(mn, __shfl_xor(mn, o));
    const float w = __expf(mn - e);
    float s = w;
#pragma unroll
    for (int o = 32; o; o >>= 1) s += __shfl_xor(s, o);
    const float a = gs * w / s;
    *(__bf16*)(sA + c*256 + ((l*2) ^ ((c&15)<<4))) = (__bf16)a;
  }
  bar_lgkm();

  // ================= Phase 3: O^T[i][c] = sum_d p[d][i] A[c][d] =============
  char* sT = sH;                   // [256 i][144B] padded rows (36864B)
  const char* pP = sT + (size_t)(wv8*32 + l31)*144;

  for (int st = 0; st < NS; ++st) {
    // transpose-convert current tile -> sT
#pragma unroll
    for (int mm = 0; mm < 2; ++mm) {
      const int row = rwb + mm*2;
#pragma unroll
      for (int jj = 0; jj < 4; ++jj) {
        const int i = row*64 + e16*4 + jj;
        bf4 qv;
        qv[0] = (__bf16)F4E(ra[mm*4+0], jj);
        qv[1] = (__bf16)F4E(ra[mm*4+1], jj);
        qv[2] = (__bf16)F4E(ra[mm*4+2], jj);
        qv[3] = (__bf16)F4E(ra[mm*4+3], jj);
        *(bf4*)(sT + i*144 + quad*8) = qv;
      }
    }
    // prefetch next tile
    const int sn = (st+1 < NS) ? st+1 : st;
#pragma unroll
    for (int k = 0; k < 8; ++k) {
      const int cc = k & 3, mm = k >> 2;
      ra[k] = *(const float4*)(xp + (size_t)(quad*4+cc)*HWs + (size_t)(sn*4+rwb+mm*2)*NW + e16*4);
    }
    bar_lgkm();

    f32x16 oo0, oo1;
#pragma unroll
    for (int r = 0; r < 16; ++r) { oo0[r] = 0.f; oo1[r] = 0.f; }
#pragma unroll
    for (int k0 = 0; k0 < 4; ++k0) {
      const int sAoff = (k0*32 + hh*16) ^ ((l31&15)<<4);
      const bf8 pa = *(const bf8*)(pP + k0*32 + hh*16);
      const bf8 b0 = *(const bf8*)(sA + (size_t)l31*256 + sAoff);
      const bf8 b1 = *(const bf8*)(sA + (size_t)(32+l31)*256 + sAoff);
      oo0 = __builtin_amdgcn_mfma_f32_32x32x16_bf16(pa, b0, oo0, 0, 0, 0);
      oo1 = __builtin_amdgcn_mfma_f32_32x32x16_bf16(pa, b1, oo1, 0, 0, 0);
    }

#pragma unroll
    for (int rq = 0; rq < 4; ++rq) {
      const int iloc = wv8*32 + rq*8 + hh*4;
      const int gi = st*256 + iloc;
      const int grow = gi >> 6, gcol = gi & 63;
      float* oprow = op + (size_t)grow*NW + gcol;
      float4 q0; q0.x = oo0[rq*4+0]; q0.y = oo0[rq*4+1];
                 q0.z = oo0[rq*4+2]; q0.w = oo0[rq*4+3];
      *(float4*)(oprow + (size_t)l31*HWs) = q0;
      float4 q1; q1.x = oo1[rq*4+0]; q1.y = oo1[rq*4+1];
                 q1.z = oo1[rq*4+2]; q1.w = oo1[rq*4+3];
      *(float4*)(oprow + (size_t)(32+l31)*HWs) = q1;
    }
    bar_lgkm();
  }
}

extern "C" void kernel_launch(void* const* d_in, const int* in_sizes, int n_in,
                              void* d_out, int out_size, void* d_ws, size_t ws_size,
                              hipStream_t stream) {
  const float* x = (const float*)d_in[0];
  const float* g = (const float*)d_in[1];
  float* o = (float*)d_out;
  spectralAgg_kernel<<<dim3(512), dim3(512), 0, stream>>>(x, g, o);
}